// Round 14
// baseline (2195.370 us; speedup 1.0000x reference)
//
#include <hip/hip_runtime.h>

typedef unsigned int u32;
typedef unsigned short u16;
typedef __attribute__((ext_vector_type(8))) short bf8v;   // 8 x bf16 (4 VGPRs)
typedef __attribute__((ext_vector_type(4))) float f32x4;  // MFMA C/D
typedef __attribute__((ext_vector_type(2))) float f32x2;  // packed f32 pairs (compiler ops)

#define NB 1024
#define NL 128
#define NH 256

// ---------------- workspace layout (byte offsets) ----------------
#define WS_WHH(g,l)  ((size_t)((g)*2+(l)) * 393216ull)
#define WS_WIHX(g)   (1572864ull + (size_t)(g)*49152ull)
#define WS_WIH1(g)   (1671168ull + (size_t)(g)*442368ull)
#define WS_WSPK      2555904ull
#define WS_WEPK      2686976ull
#define WS_AE        2818048ull                            // f32 E_ae [b][h][s]
#define WS_HTOP      (WS_AE + 134217728ull)                // bf16 [2][B][129][H]  (row0 = h0)
#define WS_HL0       (WS_HTOP + 135266304ull)              // bf16 [2][128][B][H]; ALIASED later by E_sp f16 [2][B][4][128][64]
#define WS_P         (WS_HL0 + 134217728ull)               // f32 [2][B][L]
#define WS_Q         (WS_P + 1048576ull)                   // f32 [2][B][S]

struct Ins { const float* p[23]; };

__device__ __forceinline__ u16 f2b(float f) {
  u32 u = __builtin_bit_cast(u32, f);
  u += 0x7fffu + ((u >> 16) & 1u);
  return (u16)(u >> 16);
}
__device__ __forceinline__ float b2f(u16 h) { return __builtin_bit_cast(float, ((u32)h) << 16); }
__device__ __forceinline__ u16 f2h(float f) { _Float16 h = (_Float16)f; return __builtin_bit_cast(u16, h); }
__device__ __forceinline__ float h2f(u16 h) { return (float)__builtin_bit_cast(_Float16, h); }
__device__ __forceinline__ float upk(const uint4& q, int i) {
  u32 w = (i < 2) ? q.x : (i < 4) ? q.y : (i < 6) ? q.z : q.w;
  return (i & 1) ? __builtin_bit_cast(float, w & 0xffff0000u)
                 : __builtin_bit_cast(float, w << 16);
}
__device__ __forceinline__ float frcp(float x) { return __builtin_amdgcn_rcpf(x); }
__device__ __forceinline__ float sigm(float x)  { return frcp(1.f + __expf(-x)); }
__device__ __forceinline__ float tanh_f(float x){ return 1.f - 2.f*frcp(1.f + __expf(2.f*x)); }

__device__ __forceinline__ f32x4 MF(bf8v a, bf8v b, f32x4 c) {
  return __builtin_amdgcn_mfma_f32_16x16x32_bf16(a, b, c, 0, 0, 0);
}
__device__ __forceinline__ bf8v ld8(const u16* p) {
  return __builtin_bit_cast(bf8v, *(const uint4*)p);
}
__device__ __forceinline__ bf8v cvt8(const float* p) {    // 8 f32 -> bf8v
  float4 f0 = *(const float4*)p, f1 = *(const float4*)(p+4);
  uint4 pk;
  pk.x = (u32)f2b(f0.x) | ((u32)f2b(f0.y) << 16);
  pk.y = (u32)f2b(f0.z) | ((u32)f2b(f0.w) << 16);
  pk.z = (u32)f2b(f1.x) | ((u32)f2b(f1.y) << 16);
  pk.w = (u32)f2b(f1.z) | ((u32)f2b(f1.w) << 16);
  return __builtin_bit_cast(bf8v, pk);
}
__device__ __forceinline__ f32x2 lo2(const float4& v){ f32x2 r = {v.x, v.y}; return r; }
__device__ __forceinline__ f32x2 hi2(const float4& v){ f32x2 r = {v.z, v.w}; return r; }

// hl0 store ([g][t][B][H]) and htop2 store ([g][b][129][H])
__device__ __forceinline__ void st_h(u16* hout, const u16* hlds, int t, int b0, int tid) {
  int srow = tid >> 5, scol = (tid & 31) * 8;
  *(uint4*)(hout + ((size_t)t*NB + b0 + srow)*NH + scol) = *(const uint4*)(hlds + srow*280 + scol);
}
__device__ __forceinline__ void st_h2(u16* hb, const u16* hlds, int t, int b0, int tid) {
  int srow = tid >> 5, scol = (tid & 31) * 8;
  *(uint4*)(hb + ((size_t)(b0 + srow)*129 + (t+1))*NH + scol) = *(const uint4*)(hlds + srow*280 + scol);
}

// ---------------- weight packing ----------------
__global__ void k_pack(Ins in, char* ws) {
  int tile = blockIdx.x*4 + (threadIdx.x >> 6);
  int lane = threadIdx.x & 63, llo = lane & 15, lhi = lane >> 4;
  float v[8];
  u16* dst;
  if (tile < 1536) {
    int mat = tile/384, rem = tile%384, tn = rem >> 3, kt = rem & 7;
    int g = mat >> 1, l = mat & 1;
    const float* w = in.p[4 + g*8 + l*4];
    int n = tn*16 + llo;
    #pragma unroll
    for (int i = 0; i < 8; i++) { int k = kt*32 + lhi*8 + i; v[i] = w[n*256 + k]; }
    dst = (u16*)(ws + WS_WHH(g,l)) + ((size_t)(tn*8+kt)*64 + lane)*8;
  } else if (tile < 1632) {
    int t2 = tile-1536; int g = t2/48, tn = t2%48;
    const float* w  = in.p[3+g*8];
    const float* bi = in.p[5+g*8];
    const float* bh = in.p[6+g*8];
    int n = tn*16 + llo;
    #pragma unroll
    for (int i = 0; i < 8; i++) {
      int k = lhi*8 + i;
      v[i] = (k < 3) ? w[n*3+k] : (k == 3 ? (bi[n] + (n < 512 ? bh[n] : 0.f)) : 0.f);
    }
    dst = (u16*)(ws + WS_WIHX(g)) + ((size_t)tn*64 + lane)*8;
  } else if (tile < 2496) {
    int t2 = tile-1632; int g = t2/432, rem = t2%432, tn = rem/9, kt = rem%9;
    const float* w  = in.p[7+g*8];
    const float* bi = in.p[9+g*8];
    const float* bh = in.p[10+g*8];
    int n = tn*16 + llo;
    #pragma unroll
    for (int i = 0; i < 8; i++) {
      int k = kt*32 + lhi*8 + i;
      v[i] = (k < 256) ? w[n*256+k] : (k == 256 ? (bi[n] + (n < 512 ? bh[n] : 0.f)) : 0.f);
    }
    dst = (u16*)(ws + WS_WIH1(g)) + ((size_t)(tn*9+kt)*64 + lane)*8;
  } else if (tile < 2624) {
    int t2 = tile-2496, tn = t2 >> 3, kt = t2 & 7;
    const float* aw = in.p[19]; int n = tn*16 + llo;
    #pragma unroll
    for (int i = 0; i < 8; i++) { int k = kt*32 + lhi*8 + i; v[i] = aw[n*512 + k]; }
    dst = (u16*)(ws + WS_WSPK) + ((size_t)(tn*8+kt)*64 + lane)*8;
  } else {
    int t2 = tile-2624, tn = t2 >> 3, kt = t2 & 7;
    const float* aw = in.p[19]; int n = tn*16 + llo;
    #pragma unroll
    for (int i = 0; i < 8; i++) { int k = kt*32 + lhi*8 + i; v[i] = aw[n*512 + 256 + k]; }
    dst = (u16*)(ws + WS_WEPK) + ((size_t)(tn*8+kt)*64 + lane)*8;
  }
  uint4 pk;
  pk.x = (u32)f2b(v[0]) | ((u32)f2b(v[1]) << 16);
  pk.y = (u32)f2b(v[2]) | ((u32)f2b(v[3]) << 16);
  pk.z = (u32)f2b(v[4]) | ((u32)f2b(v[5]) << 16);
  pk.w = (u32)f2b(v[6]) | ((u32)f2b(v[7]) << 16);
  *(uint4*)dst = pk;
}

// htop2[g][b][0][h] = h0[1]
__global__ void k_hall0(Ins in, char* ws) {
  int idx = blockIdx.x*256 + threadIdx.x;                  // 0..524287
  int g = idx >> 18, r = idx & 262143;                     // r = b*256 + h
  int b = r >> 8, h = r & 255;
  u16* ht = (u16*)(ws + WS_HTOP) + (size_t)g*(129ull*NB*NH);
  ht[((size_t)b*129)*NH + h] = f2b(in.p[2][262144 + r]);
}

// E_ae[b][h][s] = exp(2*sum_e eh*W_e) f32 ; q[g][b][s] = eh . Wc_g   (LDS-free)
__global__ __launch_bounds__(512, 4) void k_attn_enc(Ins in, char* ws) {
  const float* eh = in.p[1];
  const u16* wep = (const u16*)(ws + WS_WEPK);
  float* ae = (float*)(ws + WS_AE);
  float* qo = (float*)(ws + WS_Q);
  int b = blockIdx.x, tid = threadIdx.x;
  int w = tid >> 6, lane = tid & 63, llo = lane & 15, lhi = lane >> 4;
  bf8v bf[2][8];
  #pragma unroll
  for (int nt = 0; nt < 2; nt++)
    #pragma unroll
    for (int kt = 0; kt < 8; kt++)
      bf[nt][kt] = ld8(wep + (((size_t)(2*w+nt)*8 + kt)*64 + lane)*8);
  for (int mt = 0; mt < 8; mt++) {
    bf8v af[8];
    #pragma unroll
    for (int kt = 0; kt < 8; kt++)
      af[kt] = cvt8(eh + ((size_t)(b*128 + 16*mt + llo))*256 + kt*32 + lhi*8);
    #pragma unroll
    for (int nt = 0; nt < 2; nt++) {
      f32x4 c = {0.f,0.f,0.f,0.f};
      #pragma unroll
      for (int kt = 0; kt < 8; kt++) c = MF(af[kt], bf[nt][kt], c);
      int h = (2*w+nt)*16 + llo;
      int s0 = 16*mt + 4*lhi;
      float4 st = { __expf(2.f*c[0]), __expf(2.f*c[1]), __expf(2.f*c[2]), __expf(2.f*c[3]) };
      *(float4*)(ae + (size_t)b*32768 + h*128 + s0) = st;
    }
  }
  if (tid < 256) {
    int qq = tid >> 7, s = tid & 127;
    const float* wc = in.p[21] + 256 + qq*512;
    const float* es = eh + ((size_t)(b*128 + s))*256;
    float acc = 0.f;
    #pragma unroll 1
    for (int e = 0; e < 256; e += 8) {
      float4 f0 = *(const float4*)(es + e), f1 = *(const float4*)(es + e + 4);
      acc += f0.x*wc[e] + f0.y*wc[e+1] + f0.z*wc[e+2] + f0.w*wc[e+3]
           + f1.x*wc[e+4] + f1.y*wc[e+5] + f1.z*wc[e+6] + f1.w*wc[e+7];
    }
    qo[((size_t)qq*NB + b)*128 + s] = acc;
  }
}

// ---------------- recurrent layer 0 ----------------
__global__ __launch_bounds__(512, 2) void k_rec0(Ins in, char* ws) {
  __shared__ __align__(16) u16 hlds[16*280];
  __shared__ __align__(16) u16 xpad[16*32];
  const int g = blockIdx.y, b0 = blockIdx.x*16, tid = threadIdx.x;
  const int w = tid >> 6, lane = tid & 63, llo = lane & 15, lhi = lane >> 4;

  const u16* whh = (const u16*)(ws + WS_WHH(g,0));
  const u16* wgi = (const u16*)(ws + WS_WIHX(g));
  const float* bhh = in.p[6 + g*8];
  const float* h0  = in.p[2];
  const float* recv = in.p[0];
  u16* hout = (u16*)(ws + WS_HL0) + (size_t)g*(128ull*NB*NH);

  float bhhn[2];
  #pragma unroll
  for (int p = 0; p < 2; p++) bhhn[p] = bhh[512 + 32*w + 16*p + llo];

  bf8v whhR[2][8], whhN[2][8];
  #pragma unroll
  for (int p = 0; p < 2; p++)
    #pragma unroll
    for (int kt = 0; kt < 8; kt++) {
      whhR[p][kt] = ld8(whh + (((size_t)(      2*w + p)*8 + kt)*64 + lane)*8);
      whhN[p][kt] = ld8(whh + (((size_t)(32 + 2*w + p)*8 + kt)*64 + lane)*8);
    }

  float hst[2][4];
  #pragma unroll
  for (int r = 0; r < 4; r++) {
    int row = 4*lhi + r;
    #pragma unroll
    for (int p = 0; p < 2; p++) {
      int col = 32*w + 16*p + llo;
      float hv = h0[(size_t)(b0 + row)*NH + col];
      hst[p][r] = hv;
      hlds[row*280 + col] = f2b(hv);
    }
  }
  if (tid < 256) ((u32*)xpad)[tid] = 0u;
  __syncthreads();
  if (tid < 16) {
    const float* x = recv + (size_t)(b0 + tid)*(NL*3);
    uint2 q;
    q.x = (u32)f2b(x[0]) | ((u32)f2b(x[1]) << 16);
    q.y = (u32)f2b(x[2]) | (0x3f80u << 16);
    *(uint2*)(xpad + tid*32) = q;
  }

  #pragma unroll 1
  for (int t = 0; t < NL; t++) {
    __syncthreads();
    if (t) st_h(hout, hlds, t-1, b0, tid);
    bf8v xf = ld8(xpad + llo*32 + lhi*8);
    f32x4 aR[2], aZ[2], aNi[2], aNh[2];
    #pragma unroll
    for (int p = 0; p < 2; p++) {
      f32x4 z = {0.f,0.f,0.f,0.f};
      aR[p]=z; aZ[p]=z; aNi[p]=z; aNh[p]=z;
    }
    #pragma unroll
    for (int q = 0; q < 3; q++)
      #pragma unroll
      for (int p = 0; p < 2; p++) {
        bf8v bt = ld8(wgi + ((size_t)(16*q + 2*w + p)*64 + lane)*8);
        f32x4 a0 = (q==0) ? aR[p] : (q==1) ? aZ[p] : aNi[p];
        a0 = MF(xf, bt, a0);
        if (q==0) aR[p]=a0; else if (q==1) aZ[p]=a0; else aNi[p]=a0;
      }
    #pragma unroll
    for (int kt = 0; kt < 8; kt++) {
      bf8v hf = ld8(hlds + llo*280 + kt*32 + lhi*8);
      #pragma unroll
      for (int p = 0; p < 2; p++) {
        aR[p]  = MF(hf, whhR[p][kt], aR[p]);
        bf8v bz = ld8(whh + (((size_t)(16 + 2*w + p)*8 + kt)*64 + lane)*8);
        aZ[p]  = MF(hf, bz, aZ[p]);
        aNh[p] = MF(hf, whhN[p][kt], aNh[p]);
      }
    }
    u16 hv16[2][4];
    #pragma unroll
    for (int p = 0; p < 2; p++)
      #pragma unroll
      for (int r = 0; r < 4; r++) {
        float rr = sigm(aR[p][r]);
        float zz = sigm(aZ[p][r]);
        float nn = tanh_f(aNi[p][r] + rr*(aNh[p][r] + bhhn[p]));
        float h  = nn + zz*(hst[p][r] - nn);
        hst[p][r] = h; hv16[p][r] = f2b(h);
      }
    __syncthreads();
    #pragma unroll
    for (int r = 0; r < 4; r++) {
      int row = 4*lhi + r;
      #pragma unroll
      for (int p = 0; p < 2; p++)
        hlds[row*280 + 32*w + 16*p + llo] = hv16[p][r];
    }
    if (t < NL-1 && tid < 16) {
      const float* x = recv + (size_t)(b0 + tid)*(NL*3) + (size_t)(t+1)*3;
      uint2 q;
      q.x = (u32)f2b(x[0]) | ((u32)f2b(x[1]) << 16);
      q.y = (u32)f2b(x[2]) | (0x3f80u << 16);
      *(uint2*)(xpad + tid*32) = q;
    }
  }
  __syncthreads();
  st_h(hout, hlds, NL-1, b0, tid);
}

// ---------------- recurrent layer 1: in-kernel gi chunks; writes htop2 layout ----------------
__global__ __launch_bounds__(512, 2) void k_rec1(Ins in, char* ws) {
  __shared__ __align__(16) u16 hlds[16*280];
  __shared__ __align__(16) u16 alds[64*296];
  __shared__ __align__(16) u32 gilds[4*768*9];
  const int g = blockIdx.y, b0 = blockIdx.x*16, tid = threadIdx.x;
  const int w = tid >> 6, lane = tid & 63, llo = lane & 15, lhi = lane >> 4;

  const u16* whh = (const u16*)(ws + WS_WHH(g,1));
  const u16* wgi = (const u16*)(ws + WS_WIH1(g));
  const float* bhh = in.p[10 + g*8];
  const float* h0  = in.p[2] + (size_t)(NB*NH);
  const u16* hl0 = (const u16*)(ws + WS_HL0) + (size_t)g*(128ull*NB*NH);
  u16* hout = (u16*)(ws + WS_HTOP) + (size_t)g*(129ull*NB*NH);

  float bhhn[2];
  #pragma unroll
  for (int p = 0; p < 2; p++) bhhn[p] = bhh[512 + 32*w + 16*p + llo];

  bf8v whhR[2][8], whhN[2][8];
  #pragma unroll
  for (int p = 0; p < 2; p++)
    #pragma unroll
    for (int kt = 0; kt < 8; kt++) {
      whhR[p][kt] = ld8(whh + (((size_t)(      2*w + p)*8 + kt)*64 + lane)*8);
      whhN[p][kt] = ld8(whh + (((size_t)(32 + 2*w + p)*8 + kt)*64 + lane)*8);
    }

  float hst[2][4];
  #pragma unroll
  for (int r = 0; r < 4; r++) {
    int row = 4*lhi + r;
    #pragma unroll
    for (int p = 0; p < 2; p++) {
      int col = 32*w + 16*p + llo;
      float hv = h0[(size_t)(b0 + row)*NH + col];
      hst[p][r] = hv;
      hlds[row*280 + col] = f2b(hv);
    }
  }

  bf8v af8c = {0,0,0,0,0,0,0,0};
  if (lhi == 0) af8c[0] = (short)0x3f80;

  #pragma unroll 1
  for (int t = 0; t < NL; t++) {
    __syncthreads();
    if (t) st_h2(hout, hlds, t-1, b0, tid);
    if ((t & 3) == 0) {
      for (int c = tid; c < 2048; c += 512) {
        int row = c >> 5, cc = c & 31;
        *(uint4*)(alds + row*296 + cc*8) =
          *(const uint4*)(hl0 + ((size_t)(t + (row>>4))*NB + b0 + (row&15))*NH + cc*8);
      }
      __syncthreads();
      #pragma unroll 1
      for (int qq = 0; qq < 3; qq++) {
        f32x4 acc[2][4];
        #pragma unroll
        for (int p = 0; p < 2; p++)
          #pragma unroll
          for (int mt = 0; mt < 4; mt++) { f32x4 z = {0.f,0.f,0.f,0.f}; acc[p][mt] = z; }
        #pragma unroll 1
        for (int kt = 0; kt < 9; kt++) {
          bf8v b0t = ld8(wgi + (((size_t)(16*qq + 2*w + 0)*9 + kt)*64 + lane)*8);
          bf8v b1t = ld8(wgi + (((size_t)(16*qq + 2*w + 1)*9 + kt)*64 + lane)*8);
          bf8v afm[4];
          #pragma unroll
          for (int mt = 0; mt < 4; mt++)
            afm[mt] = (kt < 8) ? ld8(alds + (mt*16 + llo)*296 + kt*32 + lhi*8) : af8c;
          #pragma unroll
          for (int mt = 0; mt < 4; mt++) {
            acc[0][mt] = MF(afm[mt], b0t, acc[0][mt]);
            acc[1][mt] = MF(afm[mt], b1t, acc[1][mt]);
          }
        }
        #pragma unroll
        for (int p = 0; p < 2; p++)
          #pragma unroll
          for (int mt = 0; mt < 4; mt++) {
            int col = (16*qq + 2*w + p)*16 + llo;
            u32* G = gilds + ((size_t)mt*768 + col)*9 + 2*lhi;
            G[0] = (u32)f2b(acc[p][mt][0]) | ((u32)f2b(acc[p][mt][1]) << 16);
            G[1] = (u32)f2b(acc[p][mt][2]) | ((u32)f2b(acc[p][mt][3]) << 16);
          }
      }
      __syncthreads();
    }
    f32x4 aR[2], aZ[2], aNh[2];
    float giN[2][4];
    #pragma unroll
    for (int p = 0; p < 2; p++) {
      int colb = 32*w + 16*p + llo;
      const u32* G0 = gilds + ((size_t)(t&3)*768 +       colb)*9 + 2*lhi;
      const u32* G1 = gilds + ((size_t)(t&3)*768 + 256 + colb)*9 + 2*lhi;
      const u32* G2 = gilds + ((size_t)(t&3)*768 + 512 + colb)*9 + 2*lhi;
      u32 r0 = G0[0], r1 = G0[1], z0 = G1[0], z1 = G1[1], n0 = G2[0], n1 = G2[1];
      aR[p][0] = b2f((u16)r0); aR[p][1] = b2f((u16)(r0 >> 16));
      aR[p][2] = b2f((u16)r1); aR[p][3] = b2f((u16)(r1 >> 16));
      aZ[p][0] = b2f((u16)z0); aZ[p][1] = b2f((u16)(z0 >> 16));
      aZ[p][2] = b2f((u16)z1); aZ[p][3] = b2f((u16)(z1 >> 16));
      giN[p][0] = b2f((u16)n0); giN[p][1] = b2f((u16)(n0 >> 16));
      giN[p][2] = b2f((u16)n1); giN[p][3] = b2f((u16)(n1 >> 16));
      f32x4 z = {0.f,0.f,0.f,0.f};
      aNh[p] = z;
    }
    #pragma unroll
    for (int kt = 0; kt < 8; kt++) {
      bf8v hf = ld8(hlds + llo*280 + kt*32 + lhi*8);
      #pragma unroll
      for (int p = 0; p < 2; p++) {
        aR[p]  = MF(hf, whhR[p][kt], aR[p]);
        bf8v bz = ld8(whh + (((size_t)(16 + 2*w + p)*8 + kt)*64 + lane)*8);
        aZ[p]  = MF(hf, bz, aZ[p]);
        aNh[p] = MF(hf, whhN[p][kt], aNh[p]);
      }
    }
    u16 hv16[2][4];
    #pragma unroll
    for (int p = 0; p < 2; p++)
      #pragma unroll
      for (int r = 0; r < 4; r++) {
        float rr = sigm(aR[p][r]);
        float zz = sigm(aZ[p][r]);
        float nn = tanh_f(giN[p][r] + rr*(aNh[p][r] + bhhn[p]));
        float h  = nn + zz*(hst[p][r] - nn);
        hst[p][r] = h; hv16[p][r] = f2b(h);
      }
    __syncthreads();
    #pragma unroll
    for (int r = 0; r < 4; r++) {
      int row = 4*lhi + r;
      #pragma unroll
      for (int p = 0; p < 2; p++)
        hlds[row*280 + 32*w + 16*p + llo] = hv16[p][r];
    }
  }
  __syncthreads();
  st_h2(hout, hlds, NL-1, b0, tid);
}

// ---- E_sp quarter-major f16 [g][b][4][128 t][64 h] = exp(2*clamp(htop2 @ W_s^T)); LDS-free ----
__global__ __launch_bounds__(512, 4) void k_sp(Ins in, char* ws) {
  const int g = blockIdx.y, b = blockIdx.x, tid = threadIdx.x;
  const int w = tid >> 6, lane = tid & 63, llo = lane & 15, lhi = lane >> 4;
  const u16* ht2 = (const u16*)(ws + WS_HTOP) + (size_t)g*(129ull*NB*NH) + (size_t)b*129*NH;
  const u16* wsp = (const u16*)(ws + WS_WSPK);
  u16* esp = (u16*)(ws + WS_HL0) + ((size_t)(g*NB + b))*32768;
  bf8v bf[2][8];
  #pragma unroll
  for (int nt = 0; nt < 2; nt++)
    #pragma unroll
    for (int kt = 0; kt < 8; kt++)
      bf[nt][kt] = ld8(wsp + (((size_t)(2*w+nt)*8 + kt)*64 + lane)*8);
  for (int mt = 0; mt < 8; mt++) {
    bf8v af[8];
    #pragma unroll
    for (int kt = 0; kt < 8; kt++)
      af[kt] = ld8(ht2 + (size_t)(16*mt + llo)*NH + kt*32 + lhi*8);
    #pragma unroll
    for (int nt = 0; nt < 2; nt++) {
      f32x4 c = {0.f,0.f,0.f,0.f};
      #pragma unroll
      for (int kt = 0; kt < 8; kt++) c = MF(af[kt], bf[nt][kt], c);
      int h = (2*w+nt)*16 + llo, t0 = 16*mt + 4*lhi;
      #pragma unroll
      for (int r = 0; r < 4; r++)
        esp[(size_t)(h >> 6)*8192 + (size_t)(t0+r)*64 + (h & 63)]
          = f2h(__expf(fminf(2.f*c[r], 11.f)));
    }
  }
}

// ---------------- streaming energy: R12-exact (f16 E_sp + f32 E_ae in LDS) ----------------
__device__ __forceinline__ void quad(const float4& es, f32x2 ea0, f32x2 ea1, f32x2 ea2, f32x2 ea3,
                                     const float4& vq, f32x2& acc) {
  f32x2 D0 = ea0 * es.x + 1.f;
  f32x2 D1 = ea1 * es.y + 1.f;
  f32x2 D2 = ea2 * es.z + 1.f;
  f32x2 D3 = ea3 * es.w + 1.f;
  f32x2 na = D0 * vq.y + D1 * vq.x;
  f32x2 da = D0 * D1;
  f32x2 nb = D2 * vq.w + D3 * vq.z;
  f32x2 db = D2 * D3;
  f32x2 N  = na * db + nb * da;
  f32x2 d  = da * db;
  f32x2 r  = { frcp(d.x), frcp(d.y) };
  acc += N * r;
}

__global__ __launch_bounds__(512, 4) void k_energy(Ins in, char* ws) {
  __shared__ __align__(16) char smem[54272];
  u16*   spT = (u16*)smem;                        // [128 t][72] f16  (E_sp quarter; 144B rows)
  float* aeT = (float*)(smem + 18432);            // [64 h][132] f32  (E_ae quarter)
  float* vE  = (float*)(smem + 52224);            // 256
  float* woE = (float*)(smem + 53248);            // 256
  const int g = blockIdx.y, b = blockIdx.x, tid = threadIdx.x;
  const int w = tid >> 6, lane = tid & 63, llo = lane & 15, lhi = lane >> 4;
  const int gid = w*4 + lhi;
  const float* ae_g = (const float*)(ws + WS_AE) + (size_t)b*32768;
  const u16* esp_g  = (const u16*)(ws + WS_HL0) + ((size_t)(g*NB + b))*32768;
  const u16* ht2b   = (const u16*)(ws + WS_HTOP) + (size_t)g*(129ull*NB*NH) + (size_t)b*129*NH;
  const float* qg = (const float*)(ws + WS_Q) + ((size_t)g*NB + b)*128;
  float* pw = (float*)(ws + WS_P) + (size_t)g*(NB*NL) + (size_t)b*NL;

  for (int c = tid; c < 256; c += 512) { vE[c] = in.p[20][c]; woE[c] = in.p[21][g*512 + c]; }
  __syncthreads();
  float Vtot = 0.f;
  for (int i = 0; i < 64; i++) {
    float4 v4 = *(const float4*)(vE + i*4);
    Vtot += v4.x + v4.y + v4.z + v4.w;
  }

  f32x2 acc2[2][2][4];                             // [th][t-row][s-pair]
  #pragma unroll
  for (int th = 0; th < 2; th++)
    #pragma unroll
    for (int i = 0; i < 2; i++)
      #pragma unroll
      for (int p = 0; p < 4; p++) { f32x2 z = {0.f,0.f}; acc2[th][i][p] = z; }

  #pragma unroll 1
  for (int hq4 = 0; hq4 < 4; hq4++) {
    __syncthreads();
    for (int c = tid; c < 1024; c += 512)          // stage E_sp quarter (contiguous 16 KB)
      *(uint4*)(spT + (c>>3)*72 + (c&7)*8) = *(const uint4*)(esp_g + hq4*8192 + c*8);
    for (int c = tid; c < 2048; c += 512)          // stage E_ae quarter [64h][128s] f32
      *(float4*)(aeT + (c>>5)*132 + (c&31)*4) =
        *(const float4*)(ae_g + (size_t)(hq4*64 + (c>>5))*128 + (c&31)*4);
    __syncthreads();
    #pragma unroll 1
    for (int hq = 0; hq < 16; hq++) {
      int h0 = hq*4;
      float4 eaA[4], eaB[4];
      #pragma unroll
      for (int j = 0; j < 4; j++) {
        eaA[j] = *(const float4*)(aeT + (h0+j)*132 + 4*llo);
        eaB[j] = *(const float4*)(aeT + (h0+j)*132 + 64 + 4*llo);
      }
      float4 vq = *(const float4*)(vE + hq4*64 + h0);
      #pragma unroll
      for (int th = 0; th < 2; th++) {
        int tl = th*64 + gid*2;
        uint2 ef0 = *(const uint2*)(spT + tl*72 + h0);
        uint2 ef1 = *(const uint2*)(spT + (tl+1)*72 + h0);
        float4 es0 = { h2f((u16)ef0.x), h2f((u16)(ef0.x>>16)), h2f((u16)ef0.y), h2f((u16)(ef0.y>>16)) };
        float4 es1 = { h2f((u16)ef1.x), h2f((u16)(ef1.x>>16)), h2f((u16)ef1.y), h2f((u16)(ef1.y>>16)) };
        quad(es0, lo2(eaA[0]), lo2(eaA[1]), lo2(eaA[2]), lo2(eaA[3]), vq, acc2[th][0][0]);
        quad(es0, hi2(eaA[0]), hi2(eaA[1]), hi2(eaA[2]), hi2(eaA[3]), vq, acc2[th][0][1]);
        quad(es0, lo2(eaB[0]), lo2(eaB[1]), lo2(eaB[2]), lo2(eaB[3]), vq, acc2[th][0][2]);
        quad(es0, hi2(eaB[0]), hi2(eaB[1]), hi2(eaB[2]), hi2(eaB[3]), vq, acc2[th][0][3]);
        quad(es1, lo2(eaA[0]), lo2(eaA[1]), lo2(eaA[2]), lo2(eaA[3]), vq, acc2[th][1][0]);
        quad(es1, hi2(eaA[0]), hi2(eaA[1]), hi2(eaA[2]), hi2(eaA[3]), vq, acc2[th][1][1]);
        quad(es1, lo2(eaB[0]), lo2(eaB[1]), lo2(eaB[2]), lo2(eaB[3]), vq, acc2[th][1][2]);
        quad(es1, hi2(eaB[0]), hi2(eaB[1]), hi2(eaB[2]), hi2(eaB[3]), vq, acc2[th][1][3]);
      }
    }
  }
  // softmax over s + p = a.q + o.Wo
  #pragma unroll
  for (int th = 0; th < 2; th++)
    #pragma unroll
    for (int i = 0; i < 2; i++) {
      float en[8];
      en[0] = Vtot - 2.f*acc2[th][i][0].x; en[1] = Vtot - 2.f*acc2[th][i][0].y;
      en[2] = Vtot - 2.f*acc2[th][i][1].x; en[3] = Vtot - 2.f*acc2[th][i][1].y;
      en[4] = Vtot - 2.f*acc2[th][i][2].x; en[5] = Vtot - 2.f*acc2[th][i][2].y;
      en[6] = Vtot - 2.f*acc2[th][i][3].x; en[7] = Vtot - 2.f*acc2[th][i][3].y;
      float mx = en[0];
      #pragma unroll
      for (int s = 1; s < 8; s++) mx = fmaxf(mx, en[s]);
      for (int d = 1; d < 16; d <<= 1) mx = fmaxf(mx, __shfl_xor(mx, d));
      float sum = 0.f, aw[8];
      #pragma unroll
      for (int s = 0; s < 8; s++) { float e = __expf(en[s] - mx); aw[s] = e; sum += e; }
      for (int d = 1; d < 16; d <<= 1) sum += __shfl_xor(sum, d);
      float dn = frcp(sum);
      int t = th*64 + gid*2 + i;
      float pv = 0.f;
      #pragma unroll
      for (int s = 0; s < 4; s++) pv += aw[s]*dn * qg[4*llo + s];
      #pragma unroll
      for (int s = 4; s < 8; s++) pv += aw[s]*dn * qg[64 + 4*llo + (s-4)];
      uint4 o0 = *(const uint4*)(ht2b + (size_t)(t+1)*NH + 8*llo);
      uint4 o1 = *(const uint4*)(ht2b + (size_t)(t+1)*NH + 128 + 8*llo);
      #pragma unroll
      for (int j = 0; j < 8; j++) {
        pv += upk(o0, j) * woE[8*llo + j];
        pv += upk(o1, j) * woE[128 + 8*llo + j];
      }
      for (int d = 1; d < 16; d <<= 1) pv += __shfl_xor(pv, d);
      if (llo == 0) pw[t] = pv;
    }
}

__global__ void k_final(Ins in, char* ws, float* out) {
  int idx = blockIdx.x*256 + threadIdx.x;
  int b = idx >> 7, t = idx & 127;
  const float* pw = (const float*)(ws + WS_P);
  float p1 = pw[(size_t)b*NL + t];
  int t2 = (t >= 117) ? 127 : (t + 10);
  float p2 = pw[(size_t)NB*NL + (size_t)b*NL + t2];
  out[idx] = sigm(p1 + p2 + in.p[22][0]);
}

extern "C" void kernel_launch(void* const* d_in, const int* in_sizes, int n_in,
                              void* d_out, int out_size, void* d_ws, size_t ws_size,
                              hipStream_t stream) {
  Ins in;
  for (int i = 0; i < 23; i++) in.p[i] = (const float*)d_in[i];
  char* ws = (char*)d_ws;
  k_pack    <<<688, 256, 0, stream>>>(in, ws);
  k_hall0   <<<2048, 256, 0, stream>>>(in, ws);
  k_attn_enc<<<1024, 512, 0, stream>>>(in, ws);
  k_rec0    <<<dim3(64, 2), 512, 0, stream>>>(in, ws);
  k_rec1    <<<dim3(64, 2), 512, 0, stream>>>(in, ws);
  k_sp      <<<dim3(1024, 2), 512, 0, stream>>>(in, ws);
  k_energy  <<<dim3(1024, 2), 512, 0, stream>>>(in, ws);
  k_final   <<<512, 256, 0, stream>>>(in, ws, (float*)d_out);
}

// Round 15
// 1886.970 us; speedup vs baseline: 1.1634x; 1.1634x over previous
//
#include <hip/hip_runtime.h>

typedef unsigned int u32;
typedef unsigned short u16;
typedef __attribute__((ext_vector_type(8))) short bf8v;   // 8 x bf16 (4 VGPRs)
typedef __attribute__((ext_vector_type(4))) float f32x4;  // MFMA C/D
typedef __attribute__((ext_vector_type(2))) float f32x2;  // packed f32 pairs (compiler ops)

#define NB 1024
#define NL 128
#define NH 256

// ---------------- workspace layout (byte offsets) ----------------
#define WS_WHH(g,l)  ((size_t)((g)*2+(l)) * 393216ull)
#define WS_WIHX(g)   (1572864ull + (size_t)(g)*49152ull)
#define WS_WIH1(g)   (1671168ull + (size_t)(g)*442368ull)
#define WS_WSPK      2555904ull
#define WS_WEPK      2686976ull
#define WS_AE        2818048ull                            // f32 E_ae [b][h][s]
#define WS_HTOP      (WS_AE + 134217728ull)                // bf16 [2][B][129][H]  (row0 = h0)
#define WS_HL0       (WS_HTOP + 135266304ull)              // bf16 [2][128][B][H]; ALIASED later by E_sp f16 [2][B][4][128][64]
#define WS_P         (WS_HL0 + 134217728ull)               // f32 [2][B][L]
#define WS_Q         (WS_P + 1048576ull)                   // f32 [2][B][S]

struct Ins { const float* p[23]; };

__device__ __forceinline__ u16 f2b(float f) {
  u32 u = __builtin_bit_cast(u32, f);
  u += 0x7fffu + ((u >> 16) & 1u);
  return (u16)(u >> 16);
}
__device__ __forceinline__ float b2f(u16 h) { return __builtin_bit_cast(float, ((u32)h) << 16); }
__device__ __forceinline__ u16 f2h(float f) { _Float16 h = (_Float16)f; return __builtin_bit_cast(u16, h); }
__device__ __forceinline__ float h2f(u16 h) { return (float)__builtin_bit_cast(_Float16, h); }
__device__ __forceinline__ float upk(const uint4& q, int i) {
  u32 w = (i < 2) ? q.x : (i < 4) ? q.y : (i < 6) ? q.z : q.w;
  return (i & 1) ? __builtin_bit_cast(float, w & 0xffff0000u)
                 : __builtin_bit_cast(float, w << 16);
}
__device__ __forceinline__ float frcp(float x) { return __builtin_amdgcn_rcpf(x); }
__device__ __forceinline__ float sigm(float x)  { return frcp(1.f + __expf(-x)); }
__device__ __forceinline__ float tanh_f(float x){ return 1.f - 2.f*frcp(1.f + __expf(2.f*x)); }

__device__ __forceinline__ f32x4 MF(bf8v a, bf8v b, f32x4 c) {
  return __builtin_amdgcn_mfma_f32_16x16x32_bf16(a, b, c, 0, 0, 0);
}
__device__ __forceinline__ bf8v ld8(const u16* p) {
  return __builtin_bit_cast(bf8v, *(const uint4*)p);
}
__device__ __forceinline__ f32x2 lo2(const float4& v){ f32x2 r = {v.x, v.y}; return r; }
__device__ __forceinline__ f32x2 hi2(const float4& v){ f32x2 r = {v.z, v.w}; return r; }

// hl0 store ([g][t][B][H]) and htop2 store ([g][b][129][H])
__device__ __forceinline__ void st_h(u16* hout, const u16* hlds, int t, int b0, int tid) {
  int srow = tid >> 5, scol = (tid & 31) * 8;
  *(uint4*)(hout + ((size_t)t*NB + b0 + srow)*NH + scol) = *(const uint4*)(hlds + srow*280 + scol);
}
__device__ __forceinline__ void st_h2(u16* hb, const u16* hlds, int t, int b0, int tid) {
  int srow = tid >> 5, scol = (tid & 31) * 8;
  *(uint4*)(hb + ((size_t)(b0 + srow)*129 + (t+1))*NH + scol) = *(const uint4*)(hlds + srow*280 + scol);
}

// ---------------- weight packing + h0-top copy (merged hall0) ----------------
__global__ void k_pack(Ins in, char* ws) {
  int lane = threadIdx.x & 63, llo = lane & 15, lhi = lane >> 4;
  if (blockIdx.x >= 688) {                                  // hall0: htop2[g][b][0][h] = h0[1]
    int idx = (blockIdx.x - 688)*256 + threadIdx.x;         // 0..524287
    int g = idx >> 18, r = idx & 262143;
    int b = r >> 8, h = r & 255;
    u16* ht = (u16*)(ws + WS_HTOP) + (size_t)g*(129ull*NB*NH);
    ht[((size_t)b*129)*NH + h] = f2b(in.p[2][262144 + r]);
    return;
  }
  int tile = blockIdx.x*4 + (threadIdx.x >> 6);
  float v[8];
  u16* dst;
  if (tile < 1536) {
    int mat = tile/384, rem = tile%384, tn = rem >> 3, kt = rem & 7;
    int g = mat >> 1, l = mat & 1;
    const float* w = in.p[4 + g*8 + l*4];
    int n = tn*16 + llo;
    #pragma unroll
    for (int i = 0; i < 8; i++) { int k = kt*32 + lhi*8 + i; v[i] = w[n*256 + k]; }
    dst = (u16*)(ws + WS_WHH(g,l)) + ((size_t)(tn*8+kt)*64 + lane)*8;
  } else if (tile < 1632) {
    int t2 = tile-1536; int g = t2/48, tn = t2%48;
    const float* w  = in.p[3+g*8];
    const float* bi = in.p[5+g*8];
    const float* bh = in.p[6+g*8];
    int n = tn*16 + llo;
    #pragma unroll
    for (int i = 0; i < 8; i++) {
      int k = lhi*8 + i;
      v[i] = (k < 3) ? w[n*3+k] : (k == 3 ? (bi[n] + (n < 512 ? bh[n] : 0.f)) : 0.f);
    }
    dst = (u16*)(ws + WS_WIHX(g)) + ((size_t)tn*64 + lane)*8;
  } else if (tile < 2496) {
    int t2 = tile-1632; int g = t2/432, rem = t2%432, tn = rem/9, kt = rem%9;
    const float* w  = in.p[7+g*8];
    const float* bi = in.p[9+g*8];
    const float* bh = in.p[10+g*8];
    int n = tn*16 + llo;
    #pragma unroll
    for (int i = 0; i < 8; i++) {
      int k = kt*32 + lhi*8 + i;
      v[i] = (k < 256) ? w[n*256+k] : (k == 256 ? (bi[n] + (n < 512 ? bh[n] : 0.f)) : 0.f);
    }
    dst = (u16*)(ws + WS_WIH1(g)) + ((size_t)(tn*9+kt)*64 + lane)*8;
  } else if (tile < 2624) {
    int t2 = tile-2496, tn = t2 >> 3, kt = t2 & 7;
    const float* aw = in.p[19]; int n = tn*16 + llo;
    #pragma unroll
    for (int i = 0; i < 8; i++) { int k = kt*32 + lhi*8 + i; v[i] = aw[n*512 + k]; }
    dst = (u16*)(ws + WS_WSPK) + ((size_t)(tn*8+kt)*64 + lane)*8;
  } else {
    int t2 = tile-2624, tn = t2 >> 3, kt = t2 & 7;
    const float* aw = in.p[19]; int n = tn*16 + llo;
    #pragma unroll
    for (int i = 0; i < 8; i++) { int k = kt*32 + lhi*8 + i; v[i] = aw[n*512 + 256 + k]; }
    dst = (u16*)(ws + WS_WEPK) + ((size_t)(tn*8+kt)*64 + lane)*8;
  }
  uint4 pk;
  pk.x = (u32)f2b(v[0]) | ((u32)f2b(v[1]) << 16);
  pk.y = (u32)f2b(v[2]) | ((u32)f2b(v[3]) << 16);
  pk.z = (u32)f2b(v[4]) | ((u32)f2b(v[5]) << 16);
  pk.w = (u32)f2b(v[6]) | ((u32)f2b(v[7]) << 16);
  *(uint4*)dst = pk;
}

// E_ae[b][h][s] = exp(2*sum_e eh*W_e) f32 ; q[g][b][s] = eh . Wc_g  (LDS-staged, R12)
__global__ __launch_bounds__(512, 2) void k_attn_enc(Ins in, char* ws) {
  __shared__ __align__(16) u16 alds[128*280];
  const float* eh = in.p[1];
  const u16* wep = (const u16*)(ws + WS_WEPK);
  float* ae = (float*)(ws + WS_AE);
  float* qo = (float*)(ws + WS_Q);
  int b = blockIdx.x, tid = threadIdx.x;
  int w = tid >> 6, lane = tid & 63, llo = lane & 15, lhi = lane >> 4;
  for (int c = tid; c < 4096; c += 512) {
    int row = c >> 5, cc = c & 31;
    const float* s = eh + ((size_t)(b*128 + row))*256 + cc*8;
    float4 f0 = *(const float4*)s, f1 = *(const float4*)(s+4);
    uint4 pk;
    pk.x = (u32)f2b(f0.x) | ((u32)f2b(f0.y) << 16);
    pk.y = (u32)f2b(f0.z) | ((u32)f2b(f0.w) << 16);
    pk.z = (u32)f2b(f1.x) | ((u32)f2b(f1.y) << 16);
    pk.w = (u32)f2b(f1.z) | ((u32)f2b(f1.w) << 16);
    *(uint4*)(alds + row*280 + cc*8) = pk;
  }
  __syncthreads();
  bf8v bf[2][8];
  #pragma unroll
  for (int nt = 0; nt < 2; nt++)
    #pragma unroll
    for (int kt = 0; kt < 8; kt++)
      bf[nt][kt] = ld8(wep + (((size_t)(2*w+nt)*8 + kt)*64 + lane)*8);
  for (int mt = 0; mt < 8; mt++) {
    bf8v af[8];
    #pragma unroll
    for (int kt = 0; kt < 8; kt++)
      af[kt] = ld8(alds + (16*mt + llo)*280 + kt*32 + lhi*8);
    #pragma unroll
    for (int nt = 0; nt < 2; nt++) {
      f32x4 c = {0.f,0.f,0.f,0.f};
      #pragma unroll
      for (int kt = 0; kt < 8; kt++) c = MF(af[kt], bf[nt][kt], c);
      int h = (2*w+nt)*16 + llo;
      int s0 = 16*mt + 4*lhi;
      float4 st = { __expf(2.f*c[0]), __expf(2.f*c[1]), __expf(2.f*c[2]), __expf(2.f*c[3]) };
      *(float4*)(ae + (size_t)b*32768 + h*128 + s0) = st;
    }
  }
  if (tid < 256) {
    int qq = tid >> 7, s = tid & 127;
    const float* wc = in.p[21] + 256 + qq*512;
    float acc = 0.f;
    #pragma unroll 1
    for (int e = 0; e < 256; e += 8) {
      uint4 ev = *(const uint4*)(alds + s*280 + e);
      #pragma unroll
      for (int i = 0; i < 8; i++) acc += upk(ev, i) * wc[e + i];
    }
    qo[((size_t)qq*NB + b)*128 + s] = acc;
  }
}

// ---------------- recurrent layer 0: R,Z,N gate weights ALL cached in VGPRs ----------------
__global__ __launch_bounds__(512, 2) void k_rec0(Ins in, char* ws) {
  __shared__ __align__(16) u16 hlds[16*280];
  __shared__ __align__(16) u16 xpad[16*32];
  const int g = blockIdx.y, b0 = blockIdx.x*16, tid = threadIdx.x;
  const int w = tid >> 6, lane = tid & 63, llo = lane & 15, lhi = lane >> 4;

  const u16* whh = (const u16*)(ws + WS_WHH(g,0));
  const u16* wgi = (const u16*)(ws + WS_WIHX(g));
  const float* bhh = in.p[6 + g*8];
  const float* h0  = in.p[2];
  const float* recv = in.p[0];
  u16* hout = (u16*)(ws + WS_HL0) + (size_t)g*(128ull*NB*NH);

  float bhhn[2];
  #pragma unroll
  for (int p = 0; p < 2; p++) bhhn[p] = bhh[512 + 32*w + 16*p + llo];

  bf8v whhR[2][8], whhZ[2][8], whhN[2][8];
  #pragma unroll
  for (int p = 0; p < 2; p++)
    #pragma unroll
    for (int kt = 0; kt < 8; kt++) {
      whhR[p][kt] = ld8(whh + (((size_t)(      2*w + p)*8 + kt)*64 + lane)*8);
      whhZ[p][kt] = ld8(whh + (((size_t)(16 + 2*w + p)*8 + kt)*64 + lane)*8);
      whhN[p][kt] = ld8(whh + (((size_t)(32 + 2*w + p)*8 + kt)*64 + lane)*8);
    }

  float hst[2][4];
  #pragma unroll
  for (int r = 0; r < 4; r++) {
    int row = 4*lhi + r;
    #pragma unroll
    for (int p = 0; p < 2; p++) {
      int col = 32*w + 16*p + llo;
      float hv = h0[(size_t)(b0 + row)*NH + col];
      hst[p][r] = hv;
      hlds[row*280 + col] = f2b(hv);
    }
  }
  if (tid < 256) ((u32*)xpad)[tid] = 0u;
  __syncthreads();
  if (tid < 16) {
    const float* x = recv + (size_t)(b0 + tid)*(NL*3);
    uint2 q;
    q.x = (u32)f2b(x[0]) | ((u32)f2b(x[1]) << 16);
    q.y = (u32)f2b(x[2]) | (0x3f80u << 16);
    *(uint2*)(xpad + tid*32) = q;
  }

  #pragma unroll 1
  for (int t = 0; t < NL; t++) {
    __syncthreads();
    if (t) st_h(hout, hlds, t-1, b0, tid);
    bf8v xf = ld8(xpad + llo*32 + lhi*8);
    f32x4 aR[2], aZ[2], aNi[2], aNh[2];
    #pragma unroll
    for (int p = 0; p < 2; p++) {
      f32x4 z = {0.f,0.f,0.f,0.f};
      aR[p]=z; aZ[p]=z; aNi[p]=z; aNh[p]=z;
    }
    #pragma unroll
    for (int q = 0; q < 3; q++)
      #pragma unroll
      for (int p = 0; p < 2; p++) {
        bf8v bt = ld8(wgi + ((size_t)(16*q + 2*w + p)*64 + lane)*8);
        f32x4 a0 = (q==0) ? aR[p] : (q==1) ? aZ[p] : aNi[p];
        a0 = MF(xf, bt, a0);
        if (q==0) aR[p]=a0; else if (q==1) aZ[p]=a0; else aNi[p]=a0;
      }
    #pragma unroll
    for (int kt = 0; kt < 8; kt++) {
      bf8v hf = ld8(hlds + llo*280 + kt*32 + lhi*8);
      #pragma unroll
      for (int p = 0; p < 2; p++) {
        aR[p]  = MF(hf, whhR[p][kt], aR[p]);
        aZ[p]  = MF(hf, whhZ[p][kt], aZ[p]);
        aNh[p] = MF(hf, whhN[p][kt], aNh[p]);
      }
    }
    u16 hv16[2][4];
    #pragma unroll
    for (int p = 0; p < 2; p++)
      #pragma unroll
      for (int r = 0; r < 4; r++) {
        float rr = sigm(aR[p][r]);
        float zz = sigm(aZ[p][r]);
        float nn = tanh_f(aNi[p][r] + rr*(aNh[p][r] + bhhn[p]));
        float h  = nn + zz*(hst[p][r] - nn);
        hst[p][r] = h; hv16[p][r] = f2b(h);
      }
    __syncthreads();
    #pragma unroll
    for (int r = 0; r < 4; r++) {
      int row = 4*lhi + r;
      #pragma unroll
      for (int p = 0; p < 2; p++)
        hlds[row*280 + 32*w + 16*p + llo] = hv16[p][r];
    }
    if (t < NL-1 && tid < 16) {
      const float* x = recv + (size_t)(b0 + tid)*(NL*3) + (size_t)(t+1)*3;
      uint2 q;
      q.x = (u32)f2b(x[0]) | ((u32)f2b(x[1]) << 16);
      q.y = (u32)f2b(x[2]) | (0x3f80u << 16);
      *(uint2*)(xpad + tid*32) = q;
    }
  }
  __syncthreads();
  st_h(hout, hlds, NL-1, b0, tid);
}

// ---------------- recurrent layer 1: in-kernel gi chunks; writes htop2 layout (R12) ----------------
__global__ __launch_bounds__(512, 2) void k_rec1(Ins in, char* ws) {
  __shared__ __align__(16) u16 hlds[16*280];
  __shared__ __align__(16) u16 alds[64*296];
  __shared__ __align__(16) u32 gilds[4*768*9];
  const int g = blockIdx.y, b0 = blockIdx.x*16, tid = threadIdx.x;
  const int w = tid >> 6, lane = tid & 63, llo = lane & 15, lhi = lane >> 4;

  const u16* whh = (const u16*)(ws + WS_WHH(g,1));
  const u16* wgi = (const u16*)(ws + WS_WIH1(g));
  const float* bhh = in.p[10 + g*8];
  const float* h0  = in.p[2] + (size_t)(NB*NH);
  const u16* hl0 = (const u16*)(ws + WS_HL0) + (size_t)g*(128ull*NB*NH);
  u16* hout = (u16*)(ws + WS_HTOP) + (size_t)g*(129ull*NB*NH);

  float bhhn[2];
  #pragma unroll
  for (int p = 0; p < 2; p++) bhhn[p] = bhh[512 + 32*w + 16*p + llo];

  bf8v whhR[2][8], whhN[2][8];
  #pragma unroll
  for (int p = 0; p < 2; p++)
    #pragma unroll
    for (int kt = 0; kt < 8; kt++) {
      whhR[p][kt] = ld8(whh + (((size_t)(      2*w + p)*8 + kt)*64 + lane)*8);
      whhN[p][kt] = ld8(whh + (((size_t)(32 + 2*w + p)*8 + kt)*64 + lane)*8);
    }

  float hst[2][4];
  #pragma unroll
  for (int r = 0; r < 4; r++) {
    int row = 4*lhi + r;
    #pragma unroll
    for (int p = 0; p < 2; p++) {
      int col = 32*w + 16*p + llo;
      float hv = h0[(size_t)(b0 + row)*NH + col];
      hst[p][r] = hv;
      hlds[row*280 + col] = f2b(hv);
    }
  }

  bf8v af8c = {0,0,0,0,0,0,0,0};
  if (lhi == 0) af8c[0] = (short)0x3f80;

  #pragma unroll 1
  for (int t = 0; t < NL; t++) {
    __syncthreads();
    if (t) st_h2(hout, hlds, t-1, b0, tid);
    if ((t & 3) == 0) {
      for (int c = tid; c < 2048; c += 512) {
        int row = c >> 5, cc = c & 31;
        *(uint4*)(alds + row*296 + cc*8) =
          *(const uint4*)(hl0 + ((size_t)(t + (row>>4))*NB + b0 + (row&15))*NH + cc*8);
      }
      __syncthreads();
      #pragma unroll 1
      for (int qq = 0; qq < 3; qq++) {
        f32x4 acc[2][4];
        #pragma unroll
        for (int p = 0; p < 2; p++)
          #pragma unroll
          for (int mt = 0; mt < 4; mt++) { f32x4 z = {0.f,0.f,0.f,0.f}; acc[p][mt] = z; }
        #pragma unroll 1
        for (int kt = 0; kt < 9; kt++) {
          bf8v b0t = ld8(wgi + (((size_t)(16*qq + 2*w + 0)*9 + kt)*64 + lane)*8);
          bf8v b1t = ld8(wgi + (((size_t)(16*qq + 2*w + 1)*9 + kt)*64 + lane)*8);
          bf8v afm[4];
          #pragma unroll
          for (int mt = 0; mt < 4; mt++)
            afm[mt] = (kt < 8) ? ld8(alds + (mt*16 + llo)*296 + kt*32 + lhi*8) : af8c;
          #pragma unroll
          for (int mt = 0; mt < 4; mt++) {
            acc[0][mt] = MF(afm[mt], b0t, acc[0][mt]);
            acc[1][mt] = MF(afm[mt], b1t, acc[1][mt]);
          }
        }
        #pragma unroll
        for (int p = 0; p < 2; p++)
          #pragma unroll
          for (int mt = 0; mt < 4; mt++) {
            int col = (16*qq + 2*w + p)*16 + llo;
            u32* G = gilds + ((size_t)mt*768 + col)*9 + 2*lhi;
            G[0] = (u32)f2b(acc[p][mt][0]) | ((u32)f2b(acc[p][mt][1]) << 16);
            G[1] = (u32)f2b(acc[p][mt][2]) | ((u32)f2b(acc[p][mt][3]) << 16);
          }
      }
      __syncthreads();
    }
    f32x4 aR[2], aZ[2], aNh[2];
    float giN[2][4];
    #pragma unroll
    for (int p = 0; p < 2; p++) {
      int colb = 32*w + 16*p + llo;
      const u32* G0 = gilds + ((size_t)(t&3)*768 +       colb)*9 + 2*lhi;
      const u32* G1 = gilds + ((size_t)(t&3)*768 + 256 + colb)*9 + 2*lhi;
      const u32* G2 = gilds + ((size_t)(t&3)*768 + 512 + colb)*9 + 2*lhi;
      u32 r0 = G0[0], r1 = G0[1], z0 = G1[0], z1 = G1[1], n0 = G2[0], n1 = G2[1];
      aR[p][0] = b2f((u16)r0); aR[p][1] = b2f((u16)(r0 >> 16));
      aR[p][2] = b2f((u16)r1); aR[p][3] = b2f((u16)(r1 >> 16));
      aZ[p][0] = b2f((u16)z0); aZ[p][1] = b2f((u16)(z0 >> 16));
      aZ[p][2] = b2f((u16)z1); aZ[p][3] = b2f((u16)(z1 >> 16));
      giN[p][0] = b2f((u16)n0); giN[p][1] = b2f((u16)(n0 >> 16));
      giN[p][2] = b2f((u16)n1); giN[p][3] = b2f((u16)(n1 >> 16));
      f32x4 z = {0.f,0.f,0.f,0.f};
      aNh[p] = z;
    }
    #pragma unroll
    for (int kt = 0; kt < 8; kt++) {
      bf8v hf = ld8(hlds + llo*280 + kt*32 + lhi*8);
      #pragma unroll
      for (int p = 0; p < 2; p++) {
        aR[p]  = MF(hf, whhR[p][kt], aR[p]);
        bf8v bz = ld8(whh + (((size_t)(16 + 2*w + p)*8 + kt)*64 + lane)*8);
        aZ[p]  = MF(hf, bz, aZ[p]);
        aNh[p] = MF(hf, whhN[p][kt], aNh[p]);
      }
    }
    u16 hv16[2][4];
    #pragma unroll
    for (int p = 0; p < 2; p++)
      #pragma unroll
      for (int r = 0; r < 4; r++) {
        float rr = sigm(aR[p][r]);
        float zz = sigm(aZ[p][r]);
        float nn = tanh_f(giN[p][r] + rr*(aNh[p][r] + bhhn[p]));
        float h  = nn + zz*(hst[p][r] - nn);
        hst[p][r] = h; hv16[p][r] = f2b(h);
      }
    __syncthreads();
    #pragma unroll
    for (int r = 0; r < 4; r++) {
      int row = 4*lhi + r;
      #pragma unroll
      for (int p = 0; p < 2; p++)
        hlds[row*280 + 32*w + 16*p + llo] = hv16[p][r];
    }
  }
  __syncthreads();
  st_h2(hout, hlds, NL-1, b0, tid);
}

// ---- E_sp quarter-major f16 [g][b][4][128 t][64 h] = exp(2*clamp(htop2 @ W_s^T)); LDS-staged (R12) ----
__global__ __launch_bounds__(512, 2) void k_sp(Ins in, char* ws) {
  __shared__ __align__(16) u16 alds[128*280];
  const int g = blockIdx.y, b = blockIdx.x, tid = threadIdx.x;
  const int w = tid >> 6, lane = tid & 63, llo = lane & 15, lhi = lane >> 4;
  const u16* ht2 = (const u16*)(ws + WS_HTOP) + (size_t)g*(129ull*NB*NH) + (size_t)b*129*NH;
  const u16* wsp = (const u16*)(ws + WS_WSPK);
  u16* esp = (u16*)(ws + WS_HL0) + ((size_t)(g*NB + b))*32768;
  for (int c = tid; c < 4096; c += 512) {                 // rows tt=0..127 (prev-h)
    int row = c >> 5, cc = c & 31;
    *(uint4*)(alds + row*280 + cc*8) = *(const uint4*)(ht2 + (size_t)row*NH + cc*8);
  }
  __syncthreads();
  bf8v bf[2][8];
  #pragma unroll
  for (int nt = 0; nt < 2; nt++)
    #pragma unroll
    for (int kt = 0; kt < 8; kt++)
      bf[nt][kt] = ld8(wsp + (((size_t)(2*w+nt)*8 + kt)*64 + lane)*8);
  for (int mt = 0; mt < 8; mt++) {
    bf8v af[8];
    #pragma unroll
    for (int kt = 0; kt < 8; kt++)
      af[kt] = ld8(alds + (16*mt + llo)*280 + kt*32 + lhi*8);
    #pragma unroll
    for (int nt = 0; nt < 2; nt++) {
      f32x4 c = {0.f,0.f,0.f,0.f};
      #pragma unroll
      for (int kt = 0; kt < 8; kt++) c = MF(af[kt], bf[nt][kt], c);
      int h = (2*w+nt)*16 + llo, t0 = 16*mt + 4*lhi;
      #pragma unroll
      for (int r = 0; r < 4; r++)
        esp[(size_t)(h >> 6)*8192 + (size_t)(t0+r)*64 + (h & 63)]
          = f2h(__expf(fminf(2.f*c[r], 11.f)));
    }
  }
}

// ---------------- streaming energy: R12-exact ----------------
__device__ __forceinline__ void quad(const float4& es, f32x2 ea0, f32x2 ea1, f32x2 ea2, f32x2 ea3,
                                     const float4& vq, f32x2& acc) {
  f32x2 D0 = ea0 * es.x + 1.f;
  f32x2 D1 = ea1 * es.y + 1.f;
  f32x2 D2 = ea2 * es.z + 1.f;
  f32x2 D3 = ea3 * es.w + 1.f;
  f32x2 na = D0 * vq.y + D1 * vq.x;
  f32x2 da = D0 * D1;
  f32x2 nb = D2 * vq.w + D3 * vq.z;
  f32x2 db = D2 * D3;
  f32x2 N  = na * db + nb * da;
  f32x2 d  = da * db;
  f32x2 r  = { frcp(d.x), frcp(d.y) };
  acc += N * r;
}

__global__ __launch_bounds__(512, 4) void k_energy(Ins in, char* ws) {
  __shared__ __align__(16) char smem[54272];
  u16*   spT = (u16*)smem;                        // [128 t][72] f16  (E_sp quarter; 144B rows)
  float* aeT = (float*)(smem + 18432);            // [64 h][132] f32  (E_ae quarter)
  float* vE  = (float*)(smem + 52224);            // 256
  float* woE = (float*)(smem + 53248);            // 256
  const int g = blockIdx.y, b = blockIdx.x, tid = threadIdx.x;
  const int w = tid >> 6, lane = tid & 63, llo = lane & 15, lhi = lane >> 4;
  const int gid = w*4 + lhi;
  const float* ae_g = (const float*)(ws + WS_AE) + (size_t)b*32768;
  const u16* esp_g  = (const u16*)(ws + WS_HL0) + ((size_t)(g*NB + b))*32768;
  const u16* ht2b   = (const u16*)(ws + WS_HTOP) + (size_t)g*(129ull*NB*NH) + (size_t)b*129*NH;
  const float* qg = (const float*)(ws + WS_Q) + ((size_t)g*NB + b)*128;
  float* pw = (float*)(ws + WS_P) + (size_t)g*(NB*NL) + (size_t)b*NL;

  for (int c = tid; c < 256; c += 512) { vE[c] = in.p[20][c]; woE[c] = in.p[21][g*512 + c]; }
  __syncthreads();
  float Vtot = 0.f;
  for (int i = 0; i < 64; i++) {
    float4 v4 = *(const float4*)(vE + i*4);
    Vtot += v4.x + v4.y + v4.z + v4.w;
  }

  f32x2 acc2[2][2][4];                             // [th][t-row][s-pair]
  #pragma unroll
  for (int th = 0; th < 2; th++)
    #pragma unroll
    for (int i = 0; i < 2; i++)
      #pragma unroll
      for (int p = 0; p < 4; p++) { f32x2 z = {0.f,0.f}; acc2[th][i][p] = z; }

  #pragma unroll 1
  for (int hq4 = 0; hq4 < 4; hq4++) {
    __syncthreads();
    for (int c = tid; c < 1024; c += 512)          // stage E_sp quarter (contiguous 16 KB)
      *(uint4*)(spT + (c>>3)*72 + (c&7)*8) = *(const uint4*)(esp_g + hq4*8192 + c*8);
    for (int c = tid; c < 2048; c += 512)          // stage E_ae quarter [64h][128s] f32
      *(float4*)(aeT + (c>>5)*132 + (c&31)*4) =
        *(const float4*)(ae_g + (size_t)(hq4*64 + (c>>5))*128 + (c&31)*4);
    __syncthreads();
    #pragma unroll 1
    for (int hq = 0; hq < 16; hq++) {
      int h0 = hq*4;
      float4 eaA[4], eaB[4];
      #pragma unroll
      for (int j = 0; j < 4; j++) {
        eaA[j] = *(const float4*)(aeT + (h0+j)*132 + 4*llo);
        eaB[j] = *(const float4*)(aeT + (h0+j)*132 + 64 + 4*llo);
      }
      float4 vq = *(const float4*)(vE + hq4*64 + h0);
      #pragma unroll
      for (int th = 0; th < 2; th++) {
        int tl = th*64 + gid*2;
        uint2 ef0 = *(const uint2*)(spT + tl*72 + h0);
        uint2 ef1 = *(const uint2*)(spT + (tl+1)*72 + h0);
        float4 es0 = { h2f((u16)ef0.x), h2f((u16)(ef0.x>>16)), h2f((u16)ef0.y), h2f((u16)(ef0.y>>16)) };
        float4 es1 = { h2f((u16)ef1.x), h2f((u16)(ef1.x>>16)), h2f((u16)ef1.y), h2f((u16)(ef1.y>>16)) };
        quad(es0, lo2(eaA[0]), lo2(eaA[1]), lo2(eaA[2]), lo2(eaA[3]), vq, acc2[th][0][0]);
        quad(es0, hi2(eaA[0]), hi2(eaA[1]), hi2(eaA[2]), hi2(eaA[3]), vq, acc2[th][0][1]);
        quad(es0, lo2(eaB[0]), lo2(eaB[1]), lo2(eaB[2]), lo2(eaB[3]), vq, acc2[th][0][2]);
        quad(es0, hi2(eaB[0]), hi2(eaB[1]), hi2(eaB[2]), hi2(eaB[3]), vq, acc2[th][0][3]);
        quad(es1, lo2(eaA[0]), lo2(eaA[1]), lo2(eaA[2]), lo2(eaA[3]), vq, acc2[th][1][0]);
        quad(es1, hi2(eaA[0]), hi2(eaA[1]), hi2(eaA[2]), hi2(eaA[3]), vq, acc2[th][1][1]);
        quad(es1, lo2(eaB[0]), lo2(eaB[1]), lo2(eaB[2]), lo2(eaB[3]), vq, acc2[th][1][2]);
        quad(es1, hi2(eaB[0]), hi2(eaB[1]), hi2(eaB[2]), hi2(eaB[3]), vq, acc2[th][1][3]);
      }
    }
  }
  // softmax over s + p = a.q + o.Wo
  #pragma unroll
  for (int th = 0; th < 2; th++)
    #pragma unroll
    for (int i = 0; i < 2; i++) {
      float en[8];
      en[0] = Vtot - 2.f*acc2[th][i][0].x; en[1] = Vtot - 2.f*acc2[th][i][0].y;
      en[2] = Vtot - 2.f*acc2[th][i][1].x; en[3] = Vtot - 2.f*acc2[th][i][1].y;
      en[4] = Vtot - 2.f*acc2[th][i][2].x; en[5] = Vtot - 2.f*acc2[th][i][2].y;
      en[6] = Vtot - 2.f*acc2[th][i][3].x; en[7] = Vtot - 2.f*acc2[th][i][3].y;
      float mx = en[0];
      #pragma unroll
      for (int s = 1; s < 8; s++) mx = fmaxf(mx, en[s]);
      for (int d = 1; d < 16; d <<= 1) mx = fmaxf(mx, __shfl_xor(mx, d));
      float sum = 0.f, aw[8];
      #pragma unroll
      for (int s = 0; s < 8; s++) { float e = __expf(en[s] - mx); aw[s] = e; sum += e; }
      for (int d = 1; d < 16; d <<= 1) sum += __shfl_xor(sum, d);
      float dn = frcp(sum);
      int t = th*64 + gid*2 + i;
      float pv = 0.f;
      #pragma unroll
      for (int s = 0; s < 4; s++) pv += aw[s]*dn * qg[4*llo + s];
      #pragma unroll
      for (int s = 4; s < 8; s++) pv += aw[s]*dn * qg[64 + 4*llo + (s-4)];
      uint4 o0 = *(const uint4*)(ht2b + (size_t)(t+1)*NH + 8*llo);
      uint4 o1 = *(const uint4*)(ht2b + (size_t)(t+1)*NH + 128 + 8*llo);
      #pragma unroll
      for (int j = 0; j < 8; j++) {
        pv += upk(o0, j) * woE[8*llo + j];
        pv += upk(o1, j) * woE[128 + 8*llo + j];
      }
      for (int d = 1; d < 16; d <<= 1) pv += __shfl_xor(pv, d);
      if (llo == 0) pw[t] = pv;
    }
}

__global__ void k_final(Ins in, char* ws, float* out) {
  int idx = blockIdx.x*256 + threadIdx.x;
  int b = idx >> 7, t = idx & 127;
  const float* pw = (const float*)(ws + WS_P);
  float p1 = pw[(size_t)b*NL + t];
  int t2 = (t >= 117) ? 127 : (t + 10);
  float p2 = pw[(size_t)NB*NL + (size_t)b*NL + t2];
  out[idx] = sigm(p1 + p2 + in.p[22][0]);
}

extern "C" void kernel_launch(void* const* d_in, const int* in_sizes, int n_in,
                              void* d_out, int out_size, void* d_ws, size_t ws_size,
                              hipStream_t stream) {
  Ins in;
  for (int i = 0; i < 23; i++) in.p[i] = (const float*)d_in[i];
  char* ws = (char*)d_ws;
  k_pack    <<<2736, 256, 0, stream>>>(in, ws);   // includes hall0 (blocks 688+)
  k_attn_enc<<<1024, 512, 0, stream>>>(in, ws);
  k_rec0    <<<dim3(64, 2), 512, 0, stream>>>(in, ws);
  k_rec1    <<<dim3(64, 2), 512, 0, stream>>>(in, ws);
  k_sp      <<<dim3(1024, 2), 512, 0, stream>>>(in, ws);
  k_energy  <<<dim3(1024, 2), 512, 0, stream>>>(in, ws);
  k_final   <<<512, 256, 0, stream>>>(in, ws, (float*)d_out);
}